// Round 4
// baseline (394.494 us; speedup 1.0000x reference)
//
#include <hip/hip_runtime.h>

typedef __bf16 bf16;
typedef __bf16 bf16x4 __attribute__((ext_vector_type(4)));
typedef __bf16 bf16x8 __attribute__((ext_vector_type(8)));
typedef float  f32x4  __attribute__((ext_vector_type(4)));

#define F32X4_ZERO ((f32x4){0.f, 0.f, 0.f, 0.f})

__device__ __forceinline__ f32x4 mfma16(bf16x8 a, bf16x8 b, f32x4 c) {
  return __builtin_amdgcn_mfma_f32_16x16x32_bf16(a, b, c, 0, 0, 0);
}

// ---------------------------------------------------------------- transpose
// f32 src -> bf16 transposed dst.
// src: R x C submatrix, row stride sStride; dst: C x R, row stride dStride.
// Batched over blockIdx.z. All extents multiples of 32.
__global__ void transpose2(const float* __restrict__ src, size_t sBatch, int sStride,
                           bf16* __restrict__ dst, size_t dBatch, int dStride) {
  __shared__ bf16 t[32][33];
  src += (size_t)blockIdx.z * sBatch;
  dst += (size_t)blockIdx.z * dBatch;
  int c0 = blockIdx.x * 32, r0 = blockIdx.y * 32;
#pragma unroll
  for (int i = 0; i < 4; i++) {
    int r = threadIdx.y + i * 8;
    t[r][threadIdx.x] = (bf16)src[(size_t)(r0 + r) * sStride + c0 + threadIdx.x];
  }
  __syncthreads();
#pragma unroll
  for (int i = 0; i < 4; i++) {
    int c = threadIdx.y + i * 8;
    dst[(size_t)(c0 + c) * dStride + r0 + threadIdx.x] = t[threadIdx.x][c];
  }
}

// ---------------------------------------------------------------- layernorm
// f32 in -> bf16 out. One block per row (D=1024), 256 threads, 4 elems/thread.
__global__ __launch_bounds__(256) void ln_rows(const float* __restrict__ in,
                                               const float* __restrict__ gam,
                                               const float* __restrict__ bet,
                                               bf16* __restrict__ out) {
  int row = blockIdx.x, tid = threadIdx.x;
  f32x4 x = *(const f32x4*)(in + (size_t)row * 1024 + tid * 4);
  float s = 0.f, q = 0.f;
#pragma unroll
  for (int j = 0; j < 4; j++) { s += x[j]; q += x[j] * x[j]; }
#pragma unroll
  for (int o = 1; o < 64; o <<= 1) {
    s += __shfl_xor(s, o, 64);
    q += __shfl_xor(q, o, 64);
  }
  __shared__ float red[8];
  if ((tid & 63) == 0) { red[(tid >> 6) * 2] = s; red[(tid >> 6) * 2 + 1] = q; }
  __syncthreads();
  s = red[0] + red[2] + red[4] + red[6];
  q = red[1] + red[3] + red[5] + red[7];
  float mean = s * (1.f / 1024.f);
  float var  = q * (1.f / 1024.f) - mean * mean;
  float inv  = rsqrtf(var + 1e-6f);
  bf16x4 o;
#pragma unroll
  for (int j = 0; j < 4; j++) {
    int c = tid * 4 + j;
    o[j] = (bf16)((x[j] - mean) * inv * gam[c] + bet[c]);
  }
  *(bf16x4*)(out + (size_t)row * 1024 + tid * 4) = o;
}

// ---------------------------------------------------------------- QKV GEMM
// x1[4096][1024](bf16) @ W{q,k,v}T[h][64][1024](bf16) + bias(f32).
// BM=128, BN=64, BK=32; 4 waves each own 32 rows. Register-staged LDS.
__global__ __launch_bounds__(256) void qkv_gemm(
    const bf16* __restrict__ x1,
    const bf16* __restrict__ WqT, const bf16* __restrict__ WkT, const bf16* __restrict__ WvT,
    const float* __restrict__ bq, const float* __restrict__ bk, const float* __restrict__ bv,
    bf16* __restrict__ qo, bf16* __restrict__ ko, bf16* __restrict__ vto) {
  int tid = threadIdx.x, lane = tid & 63, wv = tid >> 6;
  int mt = blockIdx.x, h = blockIdx.y, z = blockIdx.z;
  const bf16* BT; const float* bias;
  if (z == 0)      { BT = WqT; bias = bq; }
  else if (z == 1) { BT = WkT; bias = bk; }
  else             { BT = WvT; bias = bv; }
  BT += (size_t)h * 64 * 1024; bias += h * 64;
  int m0 = mt * 128;
  __shared__ __align__(16) bf16 lA[128 * 32];  // [row][k]
  __shared__ __align__(16) bf16 lB[64 * 32];
  f32x4 acc[2][4];
#pragma unroll
  for (int a = 0; a < 2; a++)
#pragma unroll
    for (int n = 0; n < 4; n++) acc[a][n] = F32X4_ZERO;

  for (int k0 = 0; k0 < 1024; k0 += 32) {
    bf16x8 va[2], vb;
#pragma unroll
    for (int s = 0; s < 2; s++) {
      int vi = tid + s * 256;
      int row = vi >> 2, kk = (vi & 3) * 8;
      va[s] = *(const bf16x8*)(x1 + (size_t)(m0 + row) * 1024 + k0 + kk);
    }
    {
      int row = tid >> 2, kk = (tid & 3) * 8;
      vb = *(const bf16x8*)(BT + (size_t)row * 1024 + k0 + kk);
    }
    __syncthreads();
#pragma unroll
    for (int s = 0; s < 2; s++) *(bf16x8*)(lA + (tid + s * 256) * 8) = va[s];
    *(bf16x8*)(lB + tid * 8) = vb;
    __syncthreads();

    bf16x8 af[2], bfr[4];
#pragma unroll
    for (int mf = 0; mf < 2; mf++)
      af[mf] = *(const bf16x8*)(lA + (wv * 32 + mf * 16 + (lane & 15)) * 32 + (lane >> 4) * 8);
#pragma unroll
    for (int nf = 0; nf < 4; nf++)
      bfr[nf] = *(const bf16x8*)(lB + (nf * 16 + (lane & 15)) * 32 + (lane >> 4) * 8);
#pragma unroll
    for (int mf = 0; mf < 2; mf++)
#pragma unroll
      for (int nf = 0; nf < 4; nf++)
        acc[mf][nf] = mfma16(af[mf], bfr[nf], acc[mf][nf]);
  }
#pragma unroll
  for (int mf = 0; mf < 2; mf++)
#pragma unroll
    for (int nf = 0; nf < 4; nf++)
#pragma unroll
      for (int i = 0; i < 4; i++) {
        int rloc = wv * 32 + mf * 16 + ((lane >> 4) << 2) + i;
        int m = m0 + rloc;
        int b = m >> 10, s = m & 1023;
        int col = nf * 16 + (lane & 15);
        float v = acc[mf][nf][i] + bias[col];
        size_t bh = (size_t)b * 16 + h;
        if (z == 0)      qo[(bh * 1024 + s) * 64 + col] = (bf16)v;
        else if (z == 1) ko[(bh * 1024 + s) * 64 + col] = (bf16)v;
        else             vto[(bh * 64 + col) * 1024 + s] = (bf16)v;
      }
}

// ---------------------------------------------------------------- attention
// One block per (b, h, 32-row q tile). Scores in LDS (bf16, stride 1040),
// in-place softmax (unnormalized; 1/sum in PV epilogue), PV via MFMA.
__global__ __launch_bounds__(256) void attn_kernel(
    const bf16* __restrict__ qb, const bf16* __restrict__ kb, const bf16* __restrict__ vtb,
    const int* __restrict__ mask, bf16* __restrict__ attnC) {
  int tid = threadIdx.x, lane = tid & 63, wv = tid >> 6;
  int qt = blockIdx.x, h = blockIdx.y, b = blockIdx.z;
  int q0 = qt * 32;
  __shared__ __align__(16) bf16 sc[32 * 1040];
  __shared__ float smask[1024];
  __shared__ float sinv[32];
  for (int i = tid; i < 1024; i += 256) smask[i] = mask[b * 1024 + i] ? 0.f : -1e9f;

  size_t bh = (size_t)b * 16 + h;
  const bf16* qp = qb + (bh * 1024 + q0) * 64;
  bf16x8 qa[2][2];
#pragma unroll
  for (int mf = 0; mf < 2; mf++)
#pragma unroll
    for (int ks = 0; ks < 2; ks++)
      qa[mf][ks] = *(const bf16x8*)(qp + (mf * 16 + (lane & 15)) * 64 + ks * 32 + (lane >> 4) * 8);

  // phase 1: raw scores q @ k^T -> LDS bf16
  const bf16* kp = kb + bh * 1024 * 64;
  for (int nf = 0; nf < 16; nf++) {
    int s0 = wv * 256 + nf * 16;
    f32x4 a0 = F32X4_ZERO, a1 = F32X4_ZERO;
#pragma unroll
    for (int ks = 0; ks < 2; ks++) {
      bf16x8 kf = *(const bf16x8*)(kp + (size_t)(s0 + (lane & 15)) * 64 + ks * 32 + (lane >> 4) * 8);
      a0 = mfma16(qa[0][ks], kf, a0);
      a1 = mfma16(qa[1][ks], kf, a1);
    }
    int col = s0 + (lane & 15);
#pragma unroll
    for (int i = 0; i < 4; i++) {
      sc[((lane >> 4) * 4 + i) * 1040 + col]      = (bf16)a0[i];
      sc[(16 + (lane >> 4) * 4 + i) * 1040 + col] = (bf16)a1[i];
    }
  }
  __syncthreads();

  // phase 2: per-row softmax, 8 threads/row, in place (unnormalized)
  {
    int r = tid >> 3, g = tid & 7;
    bf16* rowp = sc + r * 1040;
    float mx = -3.0e38f;
#pragma unroll
    for (int cc = 0; cc < 16; cc++) {
      int col = cc * 64 + g * 8;
      bf16x8 v = *(const bf16x8*)(rowp + col);
#pragma unroll
      for (int j = 0; j < 8; j++) mx = fmaxf(mx, (float)v[j] * 0.125f + smask[col + j]);
    }
#pragma unroll
    for (int o = 1; o < 8; o <<= 1) mx = fmaxf(mx, __shfl_xor(mx, o, 64));
    float sum = 0.f;
#pragma unroll
    for (int cc = 0; cc < 16; cc++) {
      int col = cc * 64 + g * 8;
      bf16x8 v = *(const bf16x8*)(rowp + col);
      bf16x8 p;
#pragma unroll
      for (int j = 0; j < 8; j++) {
        float e = __expf((float)v[j] * 0.125f + smask[col + j] - mx);
        sum += e;
        p[j] = (bf16)e;
      }
      *(bf16x8*)(rowp + col) = p;
    }
#pragma unroll
    for (int o = 1; o < 8; o <<= 1) sum += __shfl_xor(sum, o, 64);
    if (g == 0) sinv[r] = 1.0f / sum;
  }
  __syncthreads();

  // phase 3: PV; wave wv owns head-dim cols [wv*16, wv*16+16)
  const bf16* vp = vtb + (bh * 64 + wv * 16) * 1024;
  f32x4 o0 = F32X4_ZERO, o1 = F32X4_ZERO;
  for (int st = 0; st < 32; st++) {
    bf16x8 vf = *(const bf16x8*)(vp + (size_t)(lane & 15) * 1024 + st * 32 + (lane >> 4) * 8);
    bf16x8 p0 = *(const bf16x8*)(sc + (lane & 15) * 1040 + st * 32 + (lane >> 4) * 8);
    bf16x8 p1 = *(const bf16x8*)(sc + (16 + (lane & 15)) * 1040 + st * 32 + (lane >> 4) * 8);
    o0 = mfma16(p0, vf, o0);
    o1 = mfma16(p1, vf, o1);
  }
#pragma unroll
  for (int i = 0; i < 4; i++) {
    int r0 = (lane >> 4) * 4 + i;
    int col = h * 64 + wv * 16 + (lane & 15);
    attnC[((size_t)(b * 1024 + q0 + r0)) * 1024 + col]      = (bf16)(o0[i] * sinv[r0]);
    attnC[((size_t)(b * 1024 + q0 + 16 + r0)) * 1024 + col] = (bf16)(o1[i] * sinv[16 + r0]);
  }
}

// ---------------------------------------------------------------- big GEMM
// C = A[M,K](bf16) @ BT[N,K](bf16)^T (+ bias f32), fused epilogues.
// BM=BN=128, BK=32, 4 waves (2x2 of 64x64). Register-staged LDS.
enum { EPI_WO = 0, EPI_GELU = 1, EPI_ACC0 = 2, EPI_ACC = 3, EPI_FINAL = 4 };

template <int EPI>
__global__ __launch_bounds__(256) void gemm_bt(
    const bf16* __restrict__ A, const bf16* __restrict__ BT, const float* __restrict__ bias,
    int M, int N, int K,
    const float* __restrict__ resid,  // EPI_WO / EPI_FINAL: f32 residual
    float* __restrict__ facc,         // EPI_ACC0/ACC: write/accum; EPI_FINAL: read
    bf16* __restrict__ outb,          // EPI_GELU
    float* __restrict__ outf) {       // EPI_WO / EPI_FINAL
  int tid = threadIdx.x, lane = tid & 63, wv = tid >> 6;
  int m0 = blockIdx.y * 128, n0 = blockIdx.x * 128;
  int wrow = (wv >> 1) * 64, wcol = (wv & 1) * 64;
  __shared__ __align__(16) bf16 lA[128 * 32];
  __shared__ __align__(16) bf16 lB[128 * 32];
  f32x4 acc[4][4];
#pragma unroll
  for (int a = 0; a < 4; a++)
#pragma unroll
    for (int n = 0; n < 4; n++) acc[a][n] = F32X4_ZERO;

  for (int k0 = 0; k0 < K; k0 += 32) {
    bf16x8 va[2], vb[2];
#pragma unroll
    for (int s = 0; s < 2; s++) {
      int vi = tid + s * 256;
      int row = vi >> 2, kk = (vi & 3) * 8;
      va[s] = *(const bf16x8*)(A  + (size_t)(m0 + row) * K + k0 + kk);
      vb[s] = *(const bf16x8*)(BT + (size_t)(n0 + row) * K + k0 + kk);
    }
    __syncthreads();
#pragma unroll
    for (int s = 0; s < 2; s++) {
      *(bf16x8*)(lA + (tid + s * 256) * 8) = va[s];
      *(bf16x8*)(lB + (tid + s * 256) * 8) = vb[s];
    }
    __syncthreads();

    bf16x8 af[4], bfr[4];
#pragma unroll
    for (int mf = 0; mf < 4; mf++)
      af[mf] = *(const bf16x8*)(lA + (wrow + mf * 16 + (lane & 15)) * 32 + (lane >> 4) * 8);
#pragma unroll
    for (int nf = 0; nf < 4; nf++)
      bfr[nf] = *(const bf16x8*)(lB + (wcol + nf * 16 + (lane & 15)) * 32 + (lane >> 4) * 8);
#pragma unroll
    for (int mf = 0; mf < 4; mf++)
#pragma unroll
      for (int nf = 0; nf < 4; nf++)
        acc[mf][nf] = mfma16(af[mf], bfr[nf], acc[mf][nf]);
  }
#pragma unroll
  for (int mf = 0; mf < 4; mf++)
#pragma unroll
    for (int nf = 0; nf < 4; nf++)
#pragma unroll
      for (int i = 0; i < 4; i++) {
        int row = m0 + wrow + mf * 16 + ((lane >> 4) << 2) + i;
        int col = n0 + wcol + nf * 16 + (lane & 15);
        size_t idx = (size_t)row * N + col;
        float v = acc[mf][nf][i];
        if constexpr (EPI == EPI_WO) {
          outf[idx] = v + bias[col] + resid[idx];
        } else if constexpr (EPI == EPI_GELU) {
          float u = v + bias[col];
          outb[idx] = (bf16)(0.5f * u * (1.0f + erff(u * 0.70710678118654752f)));
        } else if constexpr (EPI == EPI_ACC0) {
          facc[idx] = v;
        } else if constexpr (EPI == EPI_ACC) {
          facc[idx] += v;
        } else {  // EPI_FINAL
          outf[idx] = facc[idx] + v + bias[col] + resid[idx];
        }
      }
}

// ---------------------------------------------------------------- launch
extern "C" void kernel_launch(void* const* d_in, const int* in_sizes, int n_in,
                              void* d_out, int out_size, void* d_ws, size_t ws_size,
                              hipStream_t stream) {
  const float* hidden = (const float*)d_in[0];
  const int*   mask   = (const int*)d_in[1];
  const float* Wq = (const float*)d_in[2];
  const float* bq = (const float*)d_in[3];
  const float* Wk = (const float*)d_in[4];
  const float* bk = (const float*)d_in[5];
  const float* Wv = (const float*)d_in[6];
  const float* bv = (const float*)d_in[7];
  const float* Wo = (const float*)d_in[8];
  const float* bo = (const float*)d_in[9];
  const float* ln1g = (const float*)d_in[10];
  const float* ln1b = (const float*)d_in[11];
  const float* ln2g = (const float*)d_in[12];
  const float* ln2b = (const float*)d_in[13];
  const float* W1 = (const float*)d_in[14];
  const float* b1 = (const float*)d_in[15];
  const float* W2 = (const float*)d_in[16];
  const float* b2 = (const float*)d_in[17];
  float* out = (float*)d_out;

  char* ws = (char*)d_ws;
  const size_t MB = 1ull << 20;
  dim3 tb(32, 8);
  const size_t HB = 64 * 1024;  // per-head weight elements

  if (ws_size >= 96 * MB) {
    // ---------------- simple path (88 MB) ----------------
    bf16* x1    = (bf16*)(ws + 0 * MB);   // -> attnC -> x2
    bf16* attnC = x1;
    bf16* x2    = x1;
    bf16* qbuf  = (bf16*)(ws + 8 * MB);   // -> W1T
    bf16* W1T   = qbuf;
    bf16* kbuf  = (bf16*)(ws + 16 * MB);  // -> W2T
    bf16* W2T   = kbuf;
    bf16* vtbuf = (bf16*)(ws + 24 * MB);
    float* hbuf = (float*)(ws + 32 * MB); // 16 MB f32
    bf16* WqT   = (bf16*)(ws + 48 * MB);
    bf16* WkT   = (bf16*)(ws + 50 * MB);
    bf16* WvT   = (bf16*)(ws + 52 * MB);
    bf16* WoT   = (bf16*)(ws + 54 * MB);
    bf16* gbuf  = (bf16*)(ws + 56 * MB);  // 32 MB

    transpose2<<<dim3(2, 32, 16), tb, 0, stream>>>(Wq, HB, 64, WqT, HB, 1024);
    transpose2<<<dim3(2, 32, 16), tb, 0, stream>>>(Wk, HB, 64, WkT, HB, 1024);
    transpose2<<<dim3(2, 32, 16), tb, 0, stream>>>(Wv, HB, 64, WvT, HB, 1024);
    transpose2<<<dim3(32, 32, 1), tb, 0, stream>>>(Wo, 0, 1024, WoT, 0, 1024);
    ln_rows<<<4096, 256, 0, stream>>>(hidden, ln1g, ln1b, x1);
    qkv_gemm<<<dim3(32, 16, 3), 256, 0, stream>>>(x1, WqT, WkT, WvT, bq, bk, bv,
                                                  qbuf, kbuf, vtbuf);
    attn_kernel<<<dim3(32, 16, 4), 256, 0, stream>>>(qbuf, kbuf, vtbuf, mask, attnC);
    gemm_bt<EPI_WO><<<dim3(8, 32), 256, 0, stream>>>(attnC, WoT, bo, 4096, 1024, 1024,
                                                     hidden, nullptr, nullptr, hbuf);
    ln_rows<<<4096, 256, 0, stream>>>(hbuf, ln2g, ln2b, x2);
    transpose2<<<dim3(128, 32, 1), tb, 0, stream>>>(W1, 0, 4096, W1T, 0, 1024);
    transpose2<<<dim3(32, 128, 1), tb, 0, stream>>>(W2, 0, 1024, W2T, 0, 4096);
    gemm_bt<EPI_GELU><<<dim3(32, 32), 256, 0, stream>>>(x2, W1T, b1, 4096, 4096, 1024,
                                                        nullptr, nullptr, gbuf, nullptr);
    gemm_bt<EPI_WO><<<dim3(8, 32), 256, 0, stream>>>(gbuf, W2T, b2, 4096, 1024, 4096,
                                                     hbuf, nullptr, nullptr, out);
  } else {
    // ---------------- chunked path (56 MB) ----------------
    bf16* x1     = (bf16*)(ws + 0 * MB);   // -> attnC -> x2
    bf16* attnC  = x1;
    bf16* x2     = x1;
    bf16* qbuf   = (bf16*)(ws + 8 * MB);   // -> W1Tc/W2Tc/gchunk
    bf16* W1Tc   = (bf16*)(ws + 8 * MB);   // [512][1024] 1 MB
    bf16* W2Tc   = (bf16*)(ws + 10 * MB);  // [1024][512] 1 MB
    bf16* gchunk = (bf16*)(ws + 12 * MB);  // [4096][512] 4 MB
    bf16* kbuf   = (bf16*)(ws + 16 * MB);  // -> hbuf (with vtbuf)
    bf16* vtbuf  = (bf16*)(ws + 24 * MB);
    float* hbuf  = (float*)(ws + 16 * MB); // 16 MB f32
    bf16* WqT    = (bf16*)(ws + 32 * MB);
    bf16* WkT    = (bf16*)(ws + 34 * MB);
    bf16* WvT    = (bf16*)(ws + 36 * MB);
    bf16* WoT    = (bf16*)(ws + 38 * MB);
    float* outacc = (float*)(ws + 40 * MB); // 16 MB f32

    transpose2<<<dim3(2, 32, 16), tb, 0, stream>>>(Wq, HB, 64, WqT, HB, 1024);
    transpose2<<<dim3(2, 32, 16), tb, 0, stream>>>(Wk, HB, 64, WkT, HB, 1024);
    transpose2<<<dim3(2, 32, 16), tb, 0, stream>>>(Wv, HB, 64, WvT, HB, 1024);
    transpose2<<<dim3(32, 32, 1), tb, 0, stream>>>(Wo, 0, 1024, WoT, 0, 1024);
    ln_rows<<<4096, 256, 0, stream>>>(hidden, ln1g, ln1b, x1);
    qkv_gemm<<<dim3(32, 16, 3), 256, 0, stream>>>(x1, WqT, WkT, WvT, bq, bk, bv,
                                                  qbuf, kbuf, vtbuf);
    attn_kernel<<<dim3(32, 16, 4), 256, 0, stream>>>(qbuf, kbuf, vtbuf, mask, attnC);
    gemm_bt<EPI_WO><<<dim3(8, 32), 256, 0, stream>>>(attnC, WoT, bo, 4096, 1024, 1024,
                                                     hidden, nullptr, nullptr, hbuf);
    ln_rows<<<4096, 256, 0, stream>>>(hbuf, ln2g, ln2b, x2);

    for (int c = 0; c < 8; c++) {
      transpose2<<<dim3(16, 32, 1), tb, 0, stream>>>(W1 + c * 512, 0, 4096,
                                                     W1Tc, 0, 1024);
      transpose2<<<dim3(32, 16, 1), tb, 0, stream>>>(W2 + (size_t)c * 512 * 1024, 0, 1024,
                                                     W2Tc, 0, 512);
      gemm_bt<EPI_GELU><<<dim3(4, 32), 256, 0, stream>>>(x2, W1Tc, b1 + c * 512,
                                                         4096, 512, 1024,
                                                         nullptr, nullptr, gchunk, nullptr);
      if (c == 0)
        gemm_bt<EPI_ACC0><<<dim3(8, 32), 256, 0, stream>>>(gchunk, W2Tc, b2,
                                                           4096, 1024, 512,
                                                           nullptr, outacc, nullptr, nullptr);
      else if (c < 7)
        gemm_bt<EPI_ACC><<<dim3(8, 32), 256, 0, stream>>>(gchunk, W2Tc, b2,
                                                          4096, 1024, 512,
                                                          nullptr, outacc, nullptr, nullptr);
      else
        gemm_bt<EPI_FINAL><<<dim3(8, 32), 256, 0, stream>>>(gchunk, W2Tc, b2,
                                                            4096, 1024, 512,
                                                            hbuf, outacc, nullptr, out);
    }
  }

  (void)in_sizes; (void)n_in; (void)out_size;
}

// Round 5
// 380.435 us; speedup vs baseline: 1.0370x; 1.0370x over previous
//
#include <hip/hip_runtime.h>

typedef __bf16 bf16;
typedef __bf16 bf16x4 __attribute__((ext_vector_type(4)));
typedef __bf16 bf16x8 __attribute__((ext_vector_type(8)));
typedef float  f32x4  __attribute__((ext_vector_type(4)));

#define F32X4_ZERO ((f32x4){0.f, 0.f, 0.f, 0.f})

__device__ __forceinline__ f32x4 mfma16(bf16x8 a, bf16x8 b, f32x4 c) {
  return __builtin_amdgcn_mfma_f32_16x16x32_bf16(a, b, c, 0, 0, 0);
}

__device__ __forceinline__ void gld16(const void* g, void* l) {
  // async global->LDS, 16B/lane. LDS dest = wave-uniform base + lane*16.
  __builtin_amdgcn_global_load_lds((const __attribute__((address_space(1))) void*)g,
                                   (__attribute__((address_space(3))) void*)l, 16, 0, 0);
}

// ---------------------------------------------------------------- transpose
// f32 src -> bf16 transposed dst.
__global__ void transpose2(const float* __restrict__ src, size_t sBatch, int sStride,
                           bf16* __restrict__ dst, size_t dBatch, int dStride) {
  __shared__ bf16 t[32][33];
  src += (size_t)blockIdx.z * sBatch;
  dst += (size_t)blockIdx.z * dBatch;
  int c0 = blockIdx.x * 32, r0 = blockIdx.y * 32;
#pragma unroll
  for (int i = 0; i < 4; i++) {
    int r = threadIdx.y + i * 8;
    t[r][threadIdx.x] = (bf16)src[(size_t)(r0 + r) * sStride + c0 + threadIdx.x];
  }
  __syncthreads();
#pragma unroll
  for (int i = 0; i < 4; i++) {
    int c = threadIdx.y + i * 8;
    dst[(size_t)(c0 + c) * dStride + r0 + threadIdx.x] = t[threadIdx.x][c];
  }
}

// ---------------------------------------------------------------- layernorm
__global__ __launch_bounds__(256) void ln_rows(const float* __restrict__ in,
                                               const float* __restrict__ gam,
                                               const float* __restrict__ bet,
                                               bf16* __restrict__ out) {
  int row = blockIdx.x, tid = threadIdx.x;
  f32x4 x = *(const f32x4*)(in + (size_t)row * 1024 + tid * 4);
  float s = 0.f, q = 0.f;
#pragma unroll
  for (int j = 0; j < 4; j++) { s += x[j]; q += x[j] * x[j]; }
#pragma unroll
  for (int o = 1; o < 64; o <<= 1) {
    s += __shfl_xor(s, o, 64);
    q += __shfl_xor(q, o, 64);
  }
  __shared__ float red[8];
  if ((tid & 63) == 0) { red[(tid >> 6) * 2] = s; red[(tid >> 6) * 2 + 1] = q; }
  __syncthreads();
  s = red[0] + red[2] + red[4] + red[6];
  q = red[1] + red[3] + red[5] + red[7];
  float mean = s * (1.f / 1024.f);
  float var  = q * (1.f / 1024.f) - mean * mean;
  float inv  = rsqrtf(var + 1e-6f);
  bf16x4 o;
#pragma unroll
  for (int j = 0; j < 4; j++) {
    int c = tid * 4 + j;
    o[j] = (bf16)((x[j] - mean) * inv * gam[c] + bet[c]);
  }
  *(bf16x4*)(out + (size_t)row * 1024 + tid * 4) = o;
}

// ---------------------------------------------------------------- QKV GEMM
// x1[4096][1024](bf16) @ W{q,k,v}T[h][64][1024](bf16) + bias(f32).
// BM=128, BN=64, BK=32; 4 waves each own 32 rows. global_load_lds staging.
// q output pre-scaled by 1/8 (softmax scale folded in).
__global__ __launch_bounds__(256) void qkv_gemm(
    const bf16* __restrict__ x1,
    const bf16* __restrict__ WqT, const bf16* __restrict__ WkT, const bf16* __restrict__ WvT,
    const float* __restrict__ bq, const float* __restrict__ bk, const float* __restrict__ bv,
    bf16* __restrict__ qo, bf16* __restrict__ ko, bf16* __restrict__ vto) {
  int tid = threadIdx.x, lane = tid & 63, wv = tid >> 6;
  int mt = blockIdx.x, h = blockIdx.y, z = blockIdx.z;
  const bf16* BT; const float* bias;
  if (z == 0)      { BT = WqT; bias = bq; }
  else if (z == 1) { BT = WkT; bias = bk; }
  else             { BT = WvT; bias = bv; }
  BT += (size_t)h * 64 * 1024; bias += h * 64;
  int m0 = mt * 128;
  __shared__ __align__(16) bf16 lA[128 * 32];  // [row][k], 64B rows
  __shared__ __align__(16) bf16 lB[64 * 32];
  f32x4 acc[2][4];
#pragma unroll
  for (int a = 0; a < 2; a++)
#pragma unroll
    for (int n = 0; n < 4; n++) acc[a][n] = F32X4_ZERO;

  for (int k0 = 0; k0 < 1024; k0 += 32) {
    __syncthreads();  // prior iter frag reads done before overwrite
#pragma unroll
    for (int i = 0; i < 3; i++) {
      int c = i * 4 + wv;  // 0..11: 8 chunks A, 4 chunks B (1KB each)
      if (c < 8) {
        int off = c * 1024 + lane * 16;
        gld16((const char*)x1 + ((size_t)(m0 + (off >> 6)) * 1024 + k0) * 2 + (off & 63),
              (char*)lA + c * 1024);
      } else {
        int c2 = c - 8;
        int off = c2 * 1024 + lane * 16;
        gld16((const char*)BT + ((size_t)(off >> 6) * 1024 + k0) * 2 + (off & 63),
              (char*)lB + c2 * 1024);
      }
    }
    __syncthreads();  // drains vmcnt (gld16 landed)

    bf16x8 af[2], bfr[4];
#pragma unroll
    for (int mf = 0; mf < 2; mf++)
      af[mf] = *(const bf16x8*)(lA + (wv * 32 + mf * 16 + (lane & 15)) * 32 + (lane >> 4) * 8);
#pragma unroll
    for (int nf = 0; nf < 4; nf++)
      bfr[nf] = *(const bf16x8*)(lB + (nf * 16 + (lane & 15)) * 32 + (lane >> 4) * 8);
#pragma unroll
    for (int mf = 0; mf < 2; mf++)
#pragma unroll
      for (int nf = 0; nf < 4; nf++)
        acc[mf][nf] = mfma16(af[mf], bfr[nf], acc[mf][nf]);
  }
#pragma unroll
  for (int mf = 0; mf < 2; mf++)
#pragma unroll
    for (int nf = 0; nf < 4; nf++)
#pragma unroll
      for (int i = 0; i < 4; i++) {
        int rloc = wv * 32 + mf * 16 + ((lane >> 4) << 2) + i;
        int m = m0 + rloc;
        int b = m >> 10, s = m & 1023;
        int col = nf * 16 + (lane & 15);
        float v = acc[mf][nf][i] + bias[col];
        size_t bh = (size_t)b * 16 + h;
        if (z == 0)      qo[(bh * 1024 + s) * 64 + col] = (bf16)(v * 0.125f);
        else if (z == 1) ko[(bh * 1024 + s) * 64 + col] = (bf16)v;
        else             vto[(bh * 64 + col) * 1024 + s] = (bf16)v;
      }
}

// ---------------------------------------------------------------- attention
// Flash-style. Block = (b, h, 128 q-rows), 4 waves x 32 rows each.
// KV tiles of 64; scores in registers; online softmax (16-lane shfl reduce);
// P staged via per-wave 32x72 LDS tile; PV from LDS + vT global.
// q is pre-scaled by 1/8.
__global__ __launch_bounds__(256) void attn_flash(
    const bf16* __restrict__ qb, const bf16* __restrict__ kb, const bf16* __restrict__ vtb,
    const int* __restrict__ mask, bf16* __restrict__ attnC) {
  int tid = threadIdx.x, lane = tid & 63, wv = tid >> 6;
  int h = blockIdx.y, b = blockIdx.z;
  int q0 = blockIdx.x * 128;
  __shared__ float smask[1024];
  __shared__ __align__(16) bf16 pb[128][72];  // P tile, padded stride (18KB)
  for (int i = tid; i < 1024; i += 256) smask[i] = mask[b * 1024 + i] ? 0.f : -1e9f;
  __syncthreads();

  size_t bh = (size_t)b * 16 + h;
  const bf16* qp = qb + (bh * 1024 + q0 + wv * 32) * 64;
  bf16x8 qa[2][2];
#pragma unroll
  for (int mf = 0; mf < 2; mf++)
#pragma unroll
    for (int kc = 0; kc < 2; kc++)
      qa[mf][kc] = *(const bf16x8*)(qp + (mf * 16 + (lane & 15)) * 64 + kc * 32 + (lane >> 4) * 8);

  const bf16* kp = kb + bh * 1024 * 64;
  const bf16* vp = vtb + bh * 64 * 1024;
  bf16* myp = &pb[wv * 32][0];

  float mrun[2][4], srun[2][4];
  f32x4 oacc[2][4];
#pragma unroll
  for (int mf = 0; mf < 2; mf++)
#pragma unroll
    for (int i = 0; i < 4; i++) {
      mrun[mf][i] = -3.0e38f; srun[mf][i] = 0.f;
      oacc[mf][i] = F32X4_ZERO;
    }

  for (int t = 0; t < 16; t++) {
    int key0 = t * 64;
    // ---- QK^T: S[16q][64k] per mf, C-layout rows=(lane>>4)*4+i, col=lane&15
    f32x4 st[2][4];
#pragma unroll
    for (int nt = 0; nt < 4; nt++) {
      st[0][nt] = F32X4_ZERO; st[1][nt] = F32X4_ZERO;
#pragma unroll
      for (int kc = 0; kc < 2; kc++) {
        bf16x8 kf = *(const bf16x8*)(kp + (size_t)(key0 + nt * 16 + (lane & 15)) * 64 +
                                     kc * 32 + (lane >> 4) * 8);
        st[0][nt] = mfma16(qa[0][kc], kf, st[0][nt]);
        st[1][nt] = mfma16(qa[1][kc], kf, st[1][nt]);
      }
      float ms = smask[key0 + nt * 16 + (lane & 15)];
#pragma unroll
      for (int i = 0; i < 4; i++) { st[0][nt][i] += ms; st[1][nt][i] += ms; }
    }
    // ---- online softmax per row
#pragma unroll
    for (int mf = 0; mf < 2; mf++)
#pragma unroll
      for (int i = 0; i < 4; i++) {
        float tm = fmaxf(fmaxf(st[mf][0][i], st[mf][1][i]),
                         fmaxf(st[mf][2][i], st[mf][3][i]));
#pragma unroll
        for (int o = 1; o < 16; o <<= 1) tm = fmaxf(tm, __shfl_xor(tm, o, 64));
        float mnew = fmaxf(mrun[mf][i], tm);
        float resc = __expf(mrun[mf][i] - mnew);
        mrun[mf][i] = mnew;
        float ts = 0.f;
#pragma unroll
        for (int nt = 0; nt < 4; nt++) {
          float e = __expf(st[mf][nt][i] - mnew);
          st[mf][nt][i] = e;
          ts += e;
        }
#pragma unroll
        for (int o = 1; o < 16; o <<= 1) ts += __shfl_xor(ts, o, 64);
        srun[mf][i] = srun[mf][i] * resc + ts;
#pragma unroll
        for (int dn = 0; dn < 4; dn++) oacc[mf][dn][i] *= resc;
      }
    // ---- P -> per-wave LDS tile (private region, no barrier needed)
#pragma unroll
    for (int mf = 0; mf < 2; mf++)
#pragma unroll
      for (int nt = 0; nt < 4; nt++)
#pragma unroll
        for (int i = 0; i < 4; i++)
          myp[(mf * 16 + (lane >> 4) * 4 + i) * 72 + nt * 16 + (lane & 15)] =
              (bf16)st[mf][nt][i];
    // ---- PV: A = P (LDS), B = V (vT global)
#pragma unroll
    for (int kc = 0; kc < 2; kc++) {
      bf16x8 pa0 = *(const bf16x8*)(myp + (lane & 15) * 72 + kc * 32 + (lane >> 4) * 8);
      bf16x8 pa1 = *(const bf16x8*)(myp + (16 + (lane & 15)) * 72 + kc * 32 + (lane >> 4) * 8);
#pragma unroll
      for (int dn = 0; dn < 4; dn++) {
        bf16x8 vf = *(const bf16x8*)(vp + (size_t)(dn * 16 + (lane & 15)) * 1024 +
                                     key0 + kc * 32 + (lane >> 4) * 8);
        oacc[0][dn] = mfma16(pa0, vf, oacc[0][dn]);
        oacc[1][dn] = mfma16(pa1, vf, oacc[1][dn]);
      }
    }
  }
  // ---- epilogue: normalize, write [b,s,h*64+d]
#pragma unroll
  for (int mf = 0; mf < 2; mf++)
#pragma unroll
    for (int i = 0; i < 4; i++) {
      float inv = 1.0f / srun[mf][i];
      int row = q0 + wv * 32 + mf * 16 + ((lane >> 4) << 2) + i;
#pragma unroll
      for (int dn = 0; dn < 4; dn++)
        attnC[(size_t)(b * 1024 + row) * 1024 + h * 64 + dn * 16 + (lane & 15)] =
            (bf16)(oacc[mf][dn][i] * inv);
    }
}

// ---------------------------------------------------------------- big GEMM
// C = A[M,K](bf16) @ BT[N,K](bf16)^T (+ bias f32), fused epilogues.
// BM=BN=128, BK=32, 4 waves (2x2 of 64x64). global_load_lds staging.
enum { EPI_WO = 0, EPI_GELU = 1, EPI_ACC0 = 2, EPI_ACC = 3, EPI_FINAL = 4 };

template <int EPI>
__global__ __launch_bounds__(256) void gemm_bt(
    const bf16* __restrict__ A, const bf16* __restrict__ BT, const float* __restrict__ bias,
    int M, int N, int K,
    const float* __restrict__ resid,  // EPI_WO / EPI_FINAL: f32 residual
    float* __restrict__ facc,         // EPI_ACC0/ACC: write/accum; EPI_FINAL: read
    bf16* __restrict__ outb,          // EPI_GELU
    float* __restrict__ outf) {       // EPI_WO / EPI_FINAL
  int tid = threadIdx.x, lane = tid & 63, wv = tid >> 6;
  int m0 = blockIdx.y * 128, n0 = blockIdx.x * 128;
  int wrow = (wv >> 1) * 64, wcol = (wv & 1) * 64;
  __shared__ __align__(16) bf16 lA[128 * 32];
  __shared__ __align__(16) bf16 lB[128 * 32];
  f32x4 acc[4][4];
#pragma unroll
  for (int a = 0; a < 4; a++)
#pragma unroll
    for (int n = 0; n < 4; n++) acc[a][n] = F32X4_ZERO;

  for (int k0 = 0; k0 < K; k0 += 32) {
    __syncthreads();
#pragma unroll
    for (int i = 0; i < 2; i++) {
      int c = i * 4 + wv;  // 8 chunks of 1KB each for A and for B
      int off = c * 1024 + lane * 16;
      int row = off >> 6, cb = off & 63;
      gld16((const char*)A  + ((size_t)(m0 + row) * K + k0) * 2 + cb, (char*)lA + c * 1024);
      gld16((const char*)BT + ((size_t)(n0 + row) * K + k0) * 2 + cb, (char*)lB + c * 1024);
    }
    __syncthreads();

    bf16x8 af[4], bfr[4];
#pragma unroll
    for (int mf = 0; mf < 4; mf++)
      af[mf] = *(const bf16x8*)(lA + (wrow + mf * 16 + (lane & 15)) * 32 + (lane >> 4) * 8);
#pragma unroll
    for (int nf = 0; nf < 4; nf++)
      bfr[nf] = *(const bf16x8*)(lB + (wcol + nf * 16 + (lane & 15)) * 32 + (lane >> 4) * 8);
#pragma unroll
    for (int mf = 0; mf < 4; mf++)
#pragma unroll
      for (int nf = 0; nf < 4; nf++)
        acc[mf][nf] = mfma16(af[mf], bfr[nf], acc[mf][nf]);
  }
#pragma unroll
  for (int mf = 0; mf < 4; mf++)
#pragma unroll
    for (int nf = 0; nf < 4; nf++)
#pragma unroll
      for (int i = 0; i < 4; i++) {
        int row = m0 + wrow + mf * 16 + ((lane >> 4) << 2) + i;
        int col = n0 + wcol + nf * 16 + (lane & 15);
        size_t idx = (size_t)row * N + col;
        float v = acc[mf][nf][i];
        if constexpr (EPI == EPI_WO) {
          outf[idx] = v + bias[col] + resid[idx];
        } else if constexpr (EPI == EPI_GELU) {
          float u = v + bias[col];
          outb[idx] = (bf16)(0.5f * u * (1.0f + erff(u * 0.70710678118654752f)));
        } else if constexpr (EPI == EPI_ACC0) {
          facc[idx] = v;
        } else if constexpr (EPI == EPI_ACC) {
          facc[idx] += v;
        } else {  // EPI_FINAL
          outf[idx] = facc[idx] + v + bias[col] + resid[idx];
        }
      }
}

// ---------------------------------------------------------------- launch
extern "C" void kernel_launch(void* const* d_in, const int* in_sizes, int n_in,
                              void* d_out, int out_size, void* d_ws, size_t ws_size,
                              hipStream_t stream) {
  const float* hidden = (const float*)d_in[0];
  const int*   mask   = (const int*)d_in[1];
  const float* Wq = (const float*)d_in[2];
  const float* bq = (const float*)d_in[3];
  const float* Wk = (const float*)d_in[4];
  const float* bk = (const float*)d_in[5];
  const float* Wv = (const float*)d_in[6];
  const float* bv = (const float*)d_in[7];
  const float* Wo = (const float*)d_in[8];
  const float* bo = (const float*)d_in[9];
  const float* ln1g = (const float*)d_in[10];
  const float* ln1b = (const float*)d_in[11];
  const float* ln2g = (const float*)d_in[12];
  const float* ln2b = (const float*)d_in[13];
  const float* W1 = (const float*)d_in[14];
  const float* b1 = (const float*)d_in[15];
  const float* W2 = (const float*)d_in[16];
  const float* b2 = (const float*)d_in[17];
  float* out = (float*)d_out;

  char* ws = (char*)d_ws;
  const size_t MB = 1ull << 20;
  dim3 tb(32, 8);
  const size_t HB = 64 * 1024;  // per-head weight elements

  if (ws_size >= 96 * MB) {
    // ---------------- simple path (88 MB) ----------------
    bf16* x1    = (bf16*)(ws + 0 * MB);   // -> attnC -> x2
    bf16* attnC = x1;
    bf16* x2    = x1;
    bf16* qbuf  = (bf16*)(ws + 8 * MB);   // -> W1T
    bf16* W1T   = qbuf;
    bf16* kbuf  = (bf16*)(ws + 16 * MB);  // -> W2T
    bf16* W2T   = kbuf;
    bf16* vtbuf = (bf16*)(ws + 24 * MB);
    float* hbuf = (float*)(ws + 32 * MB); // 16 MB f32
    bf16* WqT   = (bf16*)(ws + 48 * MB);
    bf16* WkT   = (bf16*)(ws + 50 * MB);
    bf16* WvT   = (bf16*)(ws + 52 * MB);
    bf16* WoT   = (bf16*)(ws + 54 * MB);
    bf16* gbuf  = (bf16*)(ws + 56 * MB);  // 32 MB

    transpose2<<<dim3(2, 32, 16), tb, 0, stream>>>(Wq, HB, 64, WqT, HB, 1024);
    transpose2<<<dim3(2, 32, 16), tb, 0, stream>>>(Wk, HB, 64, WkT, HB, 1024);
    transpose2<<<dim3(2, 32, 16), tb, 0, stream>>>(Wv, HB, 64, WvT, HB, 1024);
    transpose2<<<dim3(32, 32, 1), tb, 0, stream>>>(Wo, 0, 1024, WoT, 0, 1024);
    ln_rows<<<4096, 256, 0, stream>>>(hidden, ln1g, ln1b, x1);
    qkv_gemm<<<dim3(32, 16, 3), 256, 0, stream>>>(x1, WqT, WkT, WvT, bq, bk, bv,
                                                  qbuf, kbuf, vtbuf);
    attn_flash<<<dim3(8, 16, 4), 256, 0, stream>>>(qbuf, kbuf, vtbuf, mask, attnC);
    gemm_bt<EPI_WO><<<dim3(8, 32), 256, 0, stream>>>(attnC, WoT, bo, 4096, 1024, 1024,
                                                     hidden, nullptr, nullptr, hbuf);
    ln_rows<<<4096, 256, 0, stream>>>(hbuf, ln2g, ln2b, x2);
    transpose2<<<dim3(128, 32, 1), tb, 0, stream>>>(W1, 0, 4096, W1T, 0, 1024);
    transpose2<<<dim3(32, 128, 1), tb, 0, stream>>>(W2, 0, 1024, W2T, 0, 4096);
    gemm_bt<EPI_GELU><<<dim3(32, 32), 256, 0, stream>>>(x2, W1T, b1, 4096, 4096, 1024,
                                                        nullptr, nullptr, gbuf, nullptr);
    gemm_bt<EPI_WO><<<dim3(8, 32), 256, 0, stream>>>(gbuf, W2T, b2, 4096, 1024, 4096,
                                                     hbuf, nullptr, nullptr, out);
  } else {
    // ---------------- chunked path (56 MB) ----------------
    bf16* x1     = (bf16*)(ws + 0 * MB);   // -> attnC -> x2
    bf16* attnC  = x1;
    bf16* x2     = x1;
    bf16* qbuf   = (bf16*)(ws + 8 * MB);   // -> W1Tc/W2Tc/gchunk
    bf16* W1Tc   = (bf16*)(ws + 8 * MB);   // [512][1024] 1 MB
    bf16* W2Tc   = (bf16*)(ws + 10 * MB);  // [1024][512] 1 MB
    bf16* gchunk = (bf16*)(ws + 12 * MB);  // [4096][512] 4 MB
    bf16* kbuf   = (bf16*)(ws + 16 * MB);  // -> hbuf (with vtbuf)
    bf16* vtbuf  = (bf16*)(ws + 24 * MB);
    float* hbuf  = (float*)(ws + 16 * MB); // 16 MB f32
    bf16* WqT    = (bf16*)(ws + 32 * MB);
    bf16* WkT    = (bf16*)(ws + 34 * MB);
    bf16* WvT    = (bf16*)(ws + 36 * MB);
    bf16* WoT    = (bf16*)(ws + 38 * MB);
    float* outacc = (float*)(ws + 40 * MB); // 16 MB f32

    transpose2<<<dim3(2, 32, 16), tb, 0, stream>>>(Wq, HB, 64, WqT, HB, 1024);
    transpose2<<<dim3(2, 32, 16), tb, 0, stream>>>(Wk, HB, 64, WkT, HB, 1024);
    transpose2<<<dim3(2, 32, 16), tb, 0, stream>>>(Wv, HB, 64, WvT, HB, 1024);
    transpose2<<<dim3(32, 32, 1), tb, 0, stream>>>(Wo, 0, 1024, WoT, 0, 1024);
    ln_rows<<<4096, 256, 0, stream>>>(hidden, ln1g, ln1b, x1);
    qkv_gemm<<<dim3(32, 16, 3), 256, 0, stream>>>(x1, WqT, WkT, WvT, bq, bk, bv,
                                                  qbuf, kbuf, vtbuf);
    attn_flash<<<dim3(8, 16, 4), 256, 0, stream>>>(qbuf, kbuf, vtbuf, mask, attnC);
    gemm_bt<EPI_WO><<<dim3(8, 32), 256, 0, stream>>>(attnC, WoT, bo, 4096, 1024, 1024,
                                                     hidden, nullptr, nullptr, hbuf);
    ln_rows<<<4096, 256, 0, stream>>>(hbuf, ln2g, ln2b, x2);

    for (int c = 0; c < 8; c++) {
      transpose2<<<dim3(16, 32, 1), tb, 0, stream>>>(W1 + c * 512, 0, 4096,
                                                     W1Tc, 0, 1024);
      transpose2<<<dim3(32, 16, 1), tb, 0, stream>>>(W2 + (size_t)c * 512 * 1024, 0, 1024,
                                                     W2Tc, 0, 512);
      gemm_bt<EPI_GELU><<<dim3(4, 32), 256, 0, stream>>>(x2, W1Tc, b1 + c * 512,
                                                         4096, 512, 1024,
                                                         nullptr, nullptr, gchunk, nullptr);
      if (c == 0)
        gemm_bt<EPI_ACC0><<<dim3(8, 32), 256, 0, stream>>>(gchunk, W2Tc, b2,
                                                           4096, 1024, 512,
                                                           nullptr, outacc, nullptr, nullptr);
      else if (c < 7)
        gemm_bt<EPI_ACC><<<dim3(8, 32), 256, 0, stream>>>(gchunk, W2Tc, b2,
                                                          4096, 1024, 512,
                                                          nullptr, outacc, nullptr, nullptr);
      else
        gemm_bt<EPI_FINAL><<<dim3(8, 32), 256, 0, stream>>>(gchunk, W2Tc, b2,
                                                            4096, 1024, 512,
                                                            hbuf, outacc, nullptr, out);
    }
  }

  (void)in_sizes; (void)n_in; (void)out_size;
}

// Round 6
// 378.489 us; speedup vs baseline: 1.0423x; 1.0051x over previous
//
#include <hip/hip_runtime.h>

typedef __bf16 bf16;
typedef __bf16 bf16x4 __attribute__((ext_vector_type(4)));
typedef __bf16 bf16x8 __attribute__((ext_vector_type(8)));
typedef float  f32x4  __attribute__((ext_vector_type(4)));

#define F32X4_ZERO ((f32x4){0.f, 0.f, 0.f, 0.f})

__device__ __forceinline__ f32x4 mfma16(bf16x8 a, bf16x8 b, f32x4 c) {
  return __builtin_amdgcn_mfma_f32_16x16x32_bf16(a, b, c, 0, 0, 0);
}

__device__ __forceinline__ void gld16(const void* g, void* l) {
  // async global->LDS, 16B/lane. LDS dest = wave-uniform base + lane*16.
  __builtin_amdgcn_global_load_lds((const __attribute__((address_space(1))) void*)g,
                                   (__attribute__((address_space(3))) void*)l, 16, 0, 0);
}

// ---------------------------------------------------------------- transpose
// f32 src -> bf16 transposed dst.
__global__ void transpose2(const float* __restrict__ src, size_t sBatch, int sStride,
                           bf16* __restrict__ dst, size_t dBatch, int dStride) {
  __shared__ bf16 t[32][33];
  src += (size_t)blockIdx.z * sBatch;
  dst += (size_t)blockIdx.z * dBatch;
  int c0 = blockIdx.x * 32, r0 = blockIdx.y * 32;
#pragma unroll
  for (int i = 0; i < 4; i++) {
    int r = threadIdx.y + i * 8;
    t[r][threadIdx.x] = (bf16)src[(size_t)(r0 + r) * sStride + c0 + threadIdx.x];
  }
  __syncthreads();
#pragma unroll
  for (int i = 0; i < 4; i++) {
    int c = threadIdx.y + i * 8;
    dst[(size_t)(c0 + c) * dStride + r0 + threadIdx.x] = t[threadIdx.x][c];
  }
}

// ---------------------------------------------------------------- layernorm
__global__ __launch_bounds__(256) void ln_rows(const float* __restrict__ in,
                                               const float* __restrict__ gam,
                                               const float* __restrict__ bet,
                                               bf16* __restrict__ out) {
  int row = blockIdx.x, tid = threadIdx.x;
  f32x4 x = *(const f32x4*)(in + (size_t)row * 1024 + tid * 4);
  float s = 0.f, q = 0.f;
#pragma unroll
  for (int j = 0; j < 4; j++) { s += x[j]; q += x[j] * x[j]; }
#pragma unroll
  for (int o = 1; o < 64; o <<= 1) {
    s += __shfl_xor(s, o, 64);
    q += __shfl_xor(q, o, 64);
  }
  __shared__ float red[8];
  if ((tid & 63) == 0) { red[(tid >> 6) * 2] = s; red[(tid >> 6) * 2 + 1] = q; }
  __syncthreads();
  s = red[0] + red[2] + red[4] + red[6];
  q = red[1] + red[3] + red[5] + red[7];
  float mean = s * (1.f / 1024.f);
  float var  = q * (1.f / 1024.f) - mean * mean;
  float inv  = rsqrtf(var + 1e-6f);
  bf16x4 o;
#pragma unroll
  for (int j = 0; j < 4; j++) {
    int c = tid * 4 + j;
    o[j] = (bf16)((x[j] - mean) * inv * gam[c] + bet[c]);
  }
  *(bf16x4*)(out + (size_t)row * 1024 + tid * 4) = o;
}

// ---------------------------------------------------------------- QKV GEMM
// x1[4096][1024](bf16) @ WT[1024][1024](bf16, rows = h*64+d) + bias(f32,[1024]).
// Full 128x128 tile like gemm_bt; head-split + q-scale + V-transpose in epilogue.
// q pre-scaled by 1/8.
__global__ __launch_bounds__(256) void qkv_gemm(
    const bf16* __restrict__ x1,
    const bf16* __restrict__ WqT, const bf16* __restrict__ WkT, const bf16* __restrict__ WvT,
    const float* __restrict__ bq, const float* __restrict__ bk, const float* __restrict__ bv,
    bf16* __restrict__ qo, bf16* __restrict__ ko, bf16* __restrict__ vto) {
  int tid = threadIdx.x, lane = tid & 63, wv = tid >> 6;
  int z = blockIdx.z;
  const bf16* BT; const float* bias;
  if (z == 0)      { BT = WqT; bias = bq; }
  else if (z == 1) { BT = WkT; bias = bk; }
  else             { BT = WvT; bias = bv; }
  int m0 = blockIdx.y * 128, n0 = blockIdx.x * 128;
  int wrow = (wv >> 1) * 64, wcol = (wv & 1) * 64;
  __shared__ __align__(16) bf16 lA[128 * 32];
  __shared__ __align__(16) bf16 lB[128 * 32];
  f32x4 acc[4][4];
#pragma unroll
  for (int a = 0; a < 4; a++)
#pragma unroll
    for (int n = 0; n < 4; n++) acc[a][n] = F32X4_ZERO;

  for (int k0 = 0; k0 < 1024; k0 += 32) {
    __syncthreads();
#pragma unroll
    for (int i = 0; i < 2; i++) {
      int c = i * 4 + wv;
      int off = c * 1024 + lane * 16;
      int row = off >> 6, cb = off & 63;
      gld16((const char*)x1 + ((size_t)(m0 + row) * 1024 + k0) * 2 + cb, (char*)lA + c * 1024);
      gld16((const char*)BT + ((size_t)(n0 + row) * 1024 + k0) * 2 + cb, (char*)lB + c * 1024);
    }
    __syncthreads();

    bf16x8 af[4], bfr[4];
#pragma unroll
    for (int mf = 0; mf < 4; mf++)
      af[mf] = *(const bf16x8*)(lA + (wrow + mf * 16 + (lane & 15)) * 32 + (lane >> 4) * 8);
#pragma unroll
    for (int nf = 0; nf < 4; nf++)
      bfr[nf] = *(const bf16x8*)(lB + (wcol + nf * 16 + (lane & 15)) * 32 + (lane >> 4) * 8);
#pragma unroll
    for (int mf = 0; mf < 4; mf++)
#pragma unroll
      for (int nf = 0; nf < 4; nf++)
        acc[mf][nf] = mfma16(af[mf], bfr[nf], acc[mf][nf]);
  }
#pragma unroll
  for (int mf = 0; mf < 4; mf++)
#pragma unroll
    for (int nf = 0; nf < 4; nf++)
#pragma unroll
      for (int i = 0; i < 4; i++) {
        int row  = m0 + wrow + mf * 16 + ((lane >> 4) << 2) + i;
        int ncol = n0 + wcol + nf * 16 + (lane & 15);
        int bb = row >> 10, s = row & 1023, head = ncol >> 6, d = ncol & 63;
        size_t bh = (size_t)bb * 16 + head;
        float v = acc[mf][nf][i] + bias[ncol];
        if (z == 0)      qo[(bh * 1024 + s) * 64 + d] = (bf16)(v * 0.125f);
        else if (z == 1) ko[(bh * 1024 + s) * 64 + d] = (bf16)v;
        else             vto[(bh * 64 + d) * 1024 + s] = (bf16)v;
      }
}

// ---------------------------------------------------------------- attention
// Flash-style. Block = (b, h, 64 q-rows), 4 waves x 16 rows. KV tiles of 64.
// V fragments prefetched before QK^T; online softmax (16-lane shfl reduce);
// P via per-wave 16x72 LDS tile. q pre-scaled by 1/8.
__global__ __launch_bounds__(256) void attn_flash(
    const bf16* __restrict__ qb, const bf16* __restrict__ kb, const bf16* __restrict__ vtb,
    const int* __restrict__ mask, bf16* __restrict__ attnC) {
  int tid = threadIdx.x, lane = tid & 63, wv = tid >> 6;
  int h = blockIdx.y, b = blockIdx.z;
  int qrow0 = blockIdx.x * 64 + wv * 16;
  __shared__ float smask[1024];
  __shared__ __align__(16) bf16 pb[4][16][72];
  for (int i = tid; i < 1024; i += 256) smask[i] = mask[b * 1024 + i] ? 0.f : -1e9f;
  __syncthreads();

  size_t bh = (size_t)b * 16 + h;
  const bf16* qp = qb + (bh * 1024 + qrow0) * 64;
  bf16x8 qa[2];
#pragma unroll
  for (int kc = 0; kc < 2; kc++)
    qa[kc] = *(const bf16x8*)(qp + (lane & 15) * 64 + kc * 32 + (lane >> 4) * 8);

  const bf16* kp = kb + bh * 1024 * 64;
  const bf16* vp = vtb + bh * 64 * 1024;
  bf16* myp = &pb[wv][0][0];

  float mrun[4], srun[4];
  f32x4 oacc[4];
#pragma unroll
  for (int i = 0; i < 4; i++) {
    mrun[i] = -3.0e38f; srun[i] = 0.f; oacc[i] = F32X4_ZERO;
  }

  for (int t = 0; t < 16; t++) {
    int key0 = t * 64;
    // ---- V prefetch (consumed after softmax; latency hides under QK+softmax)
    bf16x8 vf[2][4];
#pragma unroll
    for (int kc = 0; kc < 2; kc++)
#pragma unroll
      for (int dn = 0; dn < 4; dn++)
        vf[kc][dn] = *(const bf16x8*)(vp + (size_t)(dn * 16 + (lane & 15)) * 1024 +
                                      key0 + kc * 32 + (lane >> 4) * 8);
    // ---- QK^T: S[16q][64k], C-layout row=(lane>>4)*4+i, col=lane&15
    f32x4 st[4];
#pragma unroll
    for (int nt = 0; nt < 4; nt++) {
      st[nt] = F32X4_ZERO;
#pragma unroll
      for (int kc = 0; kc < 2; kc++) {
        bf16x8 kf = *(const bf16x8*)(kp + (size_t)(key0 + nt * 16 + (lane & 15)) * 64 +
                                     kc * 32 + (lane >> 4) * 8);
        st[nt] = mfma16(qa[kc], kf, st[nt]);
      }
      float ms = smask[key0 + nt * 16 + (lane & 15)];
#pragma unroll
      for (int i = 0; i < 4; i++) st[nt][i] += ms;
    }
    // ---- online softmax per row (4 rows/lane-reg; 16-lane shfl reduce)
#pragma unroll
    for (int i = 0; i < 4; i++) {
      float tm = fmaxf(fmaxf(st[0][i], st[1][i]), fmaxf(st[2][i], st[3][i]));
#pragma unroll
      for (int o = 1; o < 16; o <<= 1) tm = fmaxf(tm, __shfl_xor(tm, o, 64));
      float mnew = fmaxf(mrun[i], tm);
      float resc = __expf(mrun[i] - mnew);
      mrun[i] = mnew;
      float ts = 0.f;
#pragma unroll
      for (int nt = 0; nt < 4; nt++) {
        float e = __expf(st[nt][i] - mnew);
        st[nt][i] = e;
        ts += e;
      }
#pragma unroll
      for (int o = 1; o < 16; o <<= 1) ts += __shfl_xor(ts, o, 64);
      srun[i] = srun[i] * resc + ts;
#pragma unroll
      for (int dn = 0; dn < 4; dn++) oacc[dn][i] *= resc;
    }
    // ---- P -> per-wave LDS tile (wave-private; no barrier)
#pragma unroll
    for (int nt = 0; nt < 4; nt++)
#pragma unroll
      for (int i = 0; i < 4; i++)
        myp[((lane >> 4) * 4 + i) * 72 + nt * 16 + (lane & 15)] = (bf16)st[nt][i];
    // ---- PV (V already in registers)
#pragma unroll
    for (int kc = 0; kc < 2; kc++) {
      bf16x8 pa = *(const bf16x8*)(myp + (lane & 15) * 72 + kc * 32 + (lane >> 4) * 8);
#pragma unroll
      for (int dn = 0; dn < 4; dn++)
        oacc[dn] = mfma16(pa, vf[kc][dn], oacc[dn]);
    }
  }
  // ---- epilogue: normalize, write [b,s,h*64+d]
#pragma unroll
  for (int i = 0; i < 4; i++) {
    float inv = 1.0f / srun[i];
    int row = qrow0 + ((lane >> 4) << 2) + i;
#pragma unroll
    for (int dn = 0; dn < 4; dn++)
      attnC[(size_t)(b * 1024 + row) * 1024 + h * 64 + dn * 16 + (lane & 15)] =
          (bf16)(oacc[dn][i] * inv);
  }
}

// ---------------------------------------------------------------- big GEMM
// C = A[M,K](bf16) @ BT[N,K](bf16)^T (+ bias f32), fused epilogues.
// BM=BN=128, BK=32, 4 waves (2x2 of 64x64). global_load_lds staging.
enum { EPI_WO = 0, EPI_GELU = 1, EPI_ACC0 = 2, EPI_ACC = 3, EPI_FINAL = 4 };

template <int EPI>
__global__ __launch_bounds__(256) void gemm_bt(
    const bf16* __restrict__ A, const bf16* __restrict__ BT, const float* __restrict__ bias,
    int M, int N, int K,
    const float* __restrict__ resid,  // EPI_WO / EPI_FINAL: f32 residual
    float* __restrict__ facc,         // EPI_ACC0/ACC: write/accum; EPI_FINAL: read
    bf16* __restrict__ outb,          // EPI_GELU
    float* __restrict__ outf) {       // EPI_WO / EPI_FINAL
  int tid = threadIdx.x, lane = tid & 63, wv = tid >> 6;
  int m0 = blockIdx.y * 128, n0 = blockIdx.x * 128;
  int wrow = (wv >> 1) * 64, wcol = (wv & 1) * 64;
  __shared__ __align__(16) bf16 lA[128 * 32];
  __shared__ __align__(16) bf16 lB[128 * 32];
  f32x4 acc[4][4];
#pragma unroll
  for (int a = 0; a < 4; a++)
#pragma unroll
    for (int n = 0; n < 4; n++) acc[a][n] = F32X4_ZERO;

  for (int k0 = 0; k0 < K; k0 += 32) {
    __syncthreads();
#pragma unroll
    for (int i = 0; i < 2; i++) {
      int c = i * 4 + wv;  // 8 chunks of 1KB each for A and for B
      int off = c * 1024 + lane * 16;
      int row = off >> 6, cb = off & 63;
      gld16((const char*)A  + ((size_t)(m0 + row) * K + k0) * 2 + cb, (char*)lA + c * 1024);
      gld16((const char*)BT + ((size_t)(n0 + row) * K + k0) * 2 + cb, (char*)lB + c * 1024);
    }
    __syncthreads();

    bf16x8 af[4], bfr[4];
#pragma unroll
    for (int mf = 0; mf < 4; mf++)
      af[mf] = *(const bf16x8*)(lA + (wrow + mf * 16 + (lane & 15)) * 32 + (lane >> 4) * 8);
#pragma unroll
    for (int nf = 0; nf < 4; nf++)
      bfr[nf] = *(const bf16x8*)(lB + (wcol + nf * 16 + (lane & 15)) * 32 + (lane >> 4) * 8);
#pragma unroll
    for (int mf = 0; mf < 4; mf++)
#pragma unroll
      for (int nf = 0; nf < 4; nf++)
        acc[mf][nf] = mfma16(af[mf], bfr[nf], acc[mf][nf]);
  }
#pragma unroll
  for (int mf = 0; mf < 4; mf++)
#pragma unroll
    for (int nf = 0; nf < 4; nf++)
#pragma unroll
      for (int i = 0; i < 4; i++) {
        int row = m0 + wrow + mf * 16 + ((lane >> 4) << 2) + i;
        int col = n0 + wcol + nf * 16 + (lane & 15);
        size_t idx = (size_t)row * N + col;
        float v = acc[mf][nf][i];
        if constexpr (EPI == EPI_WO) {
          outf[idx] = v + bias[col] + resid[idx];
        } else if constexpr (EPI == EPI_GELU) {
          float u = v + bias[col];
          outb[idx] = (bf16)(0.5f * u * (1.0f + erff(u * 0.70710678118654752f)));
        } else if constexpr (EPI == EPI_ACC0) {
          facc[idx] = v;
        } else if constexpr (EPI == EPI_ACC) {
          facc[idx] += v;
        } else {  // EPI_FINAL
          outf[idx] = facc[idx] + v + bias[col] + resid[idx];
        }
      }
}

// ---------------------------------------------------------------- launch
extern "C" void kernel_launch(void* const* d_in, const int* in_sizes, int n_in,
                              void* d_out, int out_size, void* d_ws, size_t ws_size,
                              hipStream_t stream) {
  const float* hidden = (const float*)d_in[0];
  const int*   mask   = (const int*)d_in[1];
  const float* Wq = (const float*)d_in[2];
  const float* bq = (const float*)d_in[3];
  const float* Wk = (const float*)d_in[4];
  const float* bk = (const float*)d_in[5];
  const float* Wv = (const float*)d_in[6];
  const float* bv = (const float*)d_in[7];
  const float* Wo = (const float*)d_in[8];
  const float* bo = (const float*)d_in[9];
  const float* ln1g = (const float*)d_in[10];
  const float* ln1b = (const float*)d_in[11];
  const float* ln2g = (const float*)d_in[12];
  const float* ln2b = (const float*)d_in[13];
  const float* W1 = (const float*)d_in[14];
  const float* b1 = (const float*)d_in[15];
  const float* W2 = (const float*)d_in[16];
  const float* b2 = (const float*)d_in[17];
  float* out = (float*)d_out;

  char* ws = (char*)d_ws;
  const size_t MB = 1ull << 20;
  dim3 tb(32, 8);
  const size_t HB = 64 * 1024;  // per-head weight elements

  if (ws_size >= 96 * MB) {
    // ---------------- simple path (88 MB) ----------------
    bf16* x1    = (bf16*)(ws + 0 * MB);   // -> attnC -> x2
    bf16* attnC = x1;
    bf16* x2    = x1;
    bf16* qbuf  = (bf16*)(ws + 8 * MB);   // -> W1T
    bf16* W1T   = qbuf;
    bf16* kbuf  = (bf16*)(ws + 16 * MB);  // -> W2T
    bf16* W2T   = kbuf;
    bf16* vtbuf = (bf16*)(ws + 24 * MB);
    float* hbuf = (float*)(ws + 32 * MB); // 16 MB f32
    bf16* WqT   = (bf16*)(ws + 48 * MB);
    bf16* WkT   = (bf16*)(ws + 50 * MB);
    bf16* WvT   = (bf16*)(ws + 52 * MB);
    bf16* WoT   = (bf16*)(ws + 54 * MB);
    bf16* gbuf  = (bf16*)(ws + 56 * MB);  // 32 MB

    transpose2<<<dim3(2, 32, 16), tb, 0, stream>>>(Wq, HB, 64, WqT, HB, 1024);
    transpose2<<<dim3(2, 32, 16), tb, 0, stream>>>(Wk, HB, 64, WkT, HB, 1024);
    transpose2<<<dim3(2, 32, 16), tb, 0, stream>>>(Wv, HB, 64, WvT, HB, 1024);
    transpose2<<<dim3(32, 32, 1), tb, 0, stream>>>(Wo, 0, 1024, WoT, 0, 1024);
    ln_rows<<<4096, 256, 0, stream>>>(hidden, ln1g, ln1b, x1);
    qkv_gemm<<<dim3(8, 32, 3), 256, 0, stream>>>(x1, WqT, WkT, WvT, bq, bk, bv,
                                                 qbuf, kbuf, vtbuf);
    attn_flash<<<dim3(16, 16, 4), 256, 0, stream>>>(qbuf, kbuf, vtbuf, mask, attnC);
    gemm_bt<EPI_WO><<<dim3(8, 32), 256, 0, stream>>>(attnC, WoT, bo, 4096, 1024, 1024,
                                                     hidden, nullptr, nullptr, hbuf);
    ln_rows<<<4096, 256, 0, stream>>>(hbuf, ln2g, ln2b, x2);
    transpose2<<<dim3(128, 32, 1), tb, 0, stream>>>(W1, 0, 4096, W1T, 0, 1024);
    transpose2<<<dim3(32, 128, 1), tb, 0, stream>>>(W2, 0, 1024, W2T, 0, 4096);
    gemm_bt<EPI_GELU><<<dim3(32, 32), 256, 0, stream>>>(x2, W1T, b1, 4096, 4096, 1024,
                                                        nullptr, nullptr, gbuf, nullptr);
    gemm_bt<EPI_WO><<<dim3(8, 32), 256, 0, stream>>>(gbuf, W2T, b2, 4096, 1024, 4096,
                                                     hbuf, nullptr, nullptr, out);
  } else {
    // ---------------- chunked path (56 MB) ----------------
    bf16* x1     = (bf16*)(ws + 0 * MB);   // -> attnC -> x2
    bf16* attnC  = x1;
    bf16* x2     = x1;
    bf16* qbuf   = (bf16*)(ws + 8 * MB);   // -> W1Tc/W2Tc/gchunk
    bf16* W1Tc   = (bf16*)(ws + 8 * MB);   // [512][1024] 1 MB
    bf16* W2Tc   = (bf16*)(ws + 10 * MB);  // [1024][512] 1 MB
    bf16* gchunk = (bf16*)(ws + 12 * MB);  // [4096][512] 4 MB
    bf16* kbuf   = (bf16*)(ws + 16 * MB);  // -> hbuf (with vtbuf)
    bf16* vtbuf  = (bf16*)(ws + 24 * MB);
    float* hbuf  = (float*)(ws + 16 * MB); // 16 MB f32
    bf16* WqT    = (bf16*)(ws + 32 * MB);
    bf16* WkT    = (bf16*)(ws + 34 * MB);
    bf16* WvT    = (bf16*)(ws + 36 * MB);
    bf16* WoT    = (bf16*)(ws + 38 * MB);
    float* outacc = (float*)(ws + 40 * MB); // 16 MB f32

    transpose2<<<dim3(2, 32, 16), tb, 0, stream>>>(Wq, HB, 64, WqT, HB, 1024);
    transpose2<<<dim3(2, 32, 16), tb, 0, stream>>>(Wk, HB, 64, WkT, HB, 1024);
    transpose2<<<dim3(2, 32, 16), tb, 0, stream>>>(Wv, HB, 64, WvT, HB, 1024);
    transpose2<<<dim3(32, 32, 1), tb, 0, stream>>>(Wo, 0, 1024, WoT, 0, 1024);
    ln_rows<<<4096, 256, 0, stream>>>(hidden, ln1g, ln1b, x1);
    qkv_gemm<<<dim3(8, 32, 3), 256, 0, stream>>>(x1, WqT, WkT, WvT, bq, bk, bv,
                                                 qbuf, kbuf, vtbuf);
    attn_flash<<<dim3(16, 16, 4), 256, 0, stream>>>(qbuf, kbuf, vtbuf, mask, attnC);
    gemm_bt<EPI_WO><<<dim3(8, 32), 256, 0, stream>>>(attnC, WoT, bo, 4096, 1024, 1024,
                                                     hidden, nullptr, nullptr, hbuf);
    ln_rows<<<4096, 256, 0, stream>>>(hbuf, ln2g, ln2b, x2);

    for (int c = 0; c < 8; c++) {
      transpose2<<<dim3(16, 32, 1), tb, 0, stream>>>(W1 + c * 512, 0, 4096,
                                                     W1Tc, 0, 1024);
      transpose2<<<dim3(32, 16, 1), tb, 0, stream>>>(W2 + (size_t)c * 512 * 1024, 0, 1024,
                                                     W2Tc, 0, 512);
      gemm_bt<EPI_GELU><<<dim3(4, 32), 256, 0, stream>>>(x2, W1Tc, b1 + c * 512,
                                                         4096, 512, 1024,
                                                         nullptr, nullptr, gchunk, nullptr);
      if (c == 0)
        gemm_bt<EPI_ACC0><<<dim3(8, 32), 256, 0, stream>>>(gchunk, W2Tc, b2,
                                                           4096, 1024, 512,
                                                           nullptr, outacc, nullptr, nullptr);
      else if (c < 7)
        gemm_bt<EPI_ACC><<<dim3(8, 32), 256, 0, stream>>>(gchunk, W2Tc, b2,
                                                          4096, 1024, 512,
                                                          nullptr, outacc, nullptr, nullptr);
      else
        gemm_bt<EPI_FINAL><<<dim3(8, 32), 256, 0, stream>>>(gchunk, W2Tc, b2,
                                                            4096, 1024, 512,
                                                            hbuf, outacc, nullptr, out);
    }
  }

  (void)in_sizes; (void)n_in; (void)out_size;
}